// Round 26
// baseline (236.043 us; speedup 1.0000x reference)
//
#include <hip/hip_runtime.h>
#include <math.h>

// Problem constants (B=8, N=2048, D=256, H=8, Dh=32)
#define BATCH 8
#define SEQ   2048
#define DIM   256
#define NHEAD 8
#define DHEAD 32
#define MROWS (BATCH*SEQ)   // 16384
#define KCAT  768           // concatenated qkv/pos K-dim
#define SZE   ((size_t)MROWS * DIM)

typedef short bf16x8 __attribute__((ext_vector_type(8)));
typedef float f32x4  __attribute__((ext_vector_type(4)));
typedef float f32x16 __attribute__((ext_vector_type(16)));

#define CLSCALE 0.25503485f   // log2(e)/sqrt(32): Q pre-scaled by this in mgemm

// raw hardware exp2 (single v_exp_f32; inputs are bounded log2-units,
// masked scores are -3e38 -> exp2 -> 0; no range reduction needed)
static __device__ __forceinline__ float exp2_raw(float x) {
    float r;
    asm("v_exp_f32 %0, %1" : "=v"(r) : "v"(x));
    return r;
}

// fp32 -> bf16 round-to-nearest-even (bits)
static __device__ __forceinline__ unsigned bf16rne(float f) {
    unsigned u = __float_as_uint(f);
    return (u + 0x7FFFu + ((u >> 16) & 1u)) >> 16;
}

// ---------------------------------------------------------------------------
// Fused fp32 -> bf16 convert of x and pos into concatenated acat[M,768]
// ---------------------------------------------------------------------------
__global__ __launch_bounds__(256) void convcat_kernel(
    const float* __restrict__ x, const float* __restrict__ pos,
    unsigned short* __restrict__ acat, int n1, int n2)
{
    int i = blockIdx.x * 256 + threadIdx.x;
    const float* s; size_t dst; int j;
    if (i < n1) {
        j = i; s = x;
        int row = j >> 5, c8 = (j & 31) * 8;
        dst = (size_t)row * KCAT + c8;
    } else {
        j = i - n1; if (j >= n2) return; s = pos;
        int row = j >> 6, c8 = (j & 63) * 8;
        dst = (size_t)row * KCAT + 256 + c8;
    }
    float4 a = ((const float4*)s)[2 * j];
    float4 b = ((const float4*)s)[2 * j + 1];
    union { unsigned short u[8]; uint4 v; } o;
    o.u[0] = bf16rne(a.x); o.u[1] = bf16rne(a.y);
    o.u[2] = bf16rne(a.z); o.u[3] = bf16rne(a.w);
    o.u[4] = bf16rne(b.x); o.u[5] = bf16rne(b.y);
    o.u[6] = bf16rne(b.z); o.u[7] = bf16rne(b.w);
    *(uint4*)&acat[dst] = o.v;
}

// ---------------------------------------------------------------------------
// All 5 weight transposes in ONE launch (960 blocks, blockIdx-range dispatch).
// ---------------------------------------------------------------------------
__global__ __launch_bounds__(256) void wtrans_all_kernel(
    const float* __restrict__ Wqkv, const float* __restrict__ Wpos,
    const float* __restrict__ W1, const float* __restrict__ W2,
    unsigned short* __restrict__ wqk, unsigned short* __restrict__ wv,
    unsigned short* __restrict__ w1, unsigned short* __restrict__ w2)
{
    int b = blockIdx.x;
    const float* src; unsigned short* dst;
    int srcN, srcColOff, dstK, dstKOff, nbx;
    if (b < 128)      {          src = Wqkv; dst = wqk; srcN = 768;  srcColOff = 0;   dstK = 768;  dstKOff = 0;   nbx = 16; }
    else if (b < 384) { b -= 128; src = Wpos; dst = wqk; srcN = 512;  srcColOff = 0;   dstK = 768;  dstKOff = 256; nbx = 16; }
    else if (b < 448) { b -= 384; src = Wqkv; dst = wv;  srcN = 768;  srcColOff = 512; dstK = 256;  dstKOff = 0;   nbx = 8;  }
    else if (b < 704) { b -= 448; src = W1;   dst = w1;  srcN = 1024; srcColOff = 0;   dstK = 256;  dstKOff = 0;   nbx = 32; }
    else              { b -= 704; src = W2;   dst = w2;  srcN = 256;  srcColOff = 0;   dstK = 1024; dstKOff = 0;   nbx = 8;  }
    const int tn0 = (b % nbx) * 32;
    const int tk0 = (b / nbx) * 32;

    __shared__ float tile[32][33];
    const int tx = threadIdx.x & 31;
    const int ty = threadIdx.x >> 5;
    #pragma unroll
    for (int r = ty; r < 32; r += 8)
        tile[r][tx] = src[(size_t)(tk0 + r) * srcN + srcColOff + tn0 + tx];
    __syncthreads();
    #pragma unroll
    for (int r = ty; r < 32; r += 8)
        dst[(size_t)(tn0 + r) * dstK + dstKOff + tk0 + tx] =
            (unsigned short)bf16rne(tile[tx][r]);
}

// ---------------------------------------------------------------------------
// bf16 MFMA GEMM body (device fn): C[M,Nc] = A[M,K] @ Wt[Nc,K]^T + bias.
// 128x128 tile at (bx,by), 4 waves 2x2, 4x4 frags of 16x16x32.
// Modes: 0 fp32 store | 1 relu->bf16 | 4 qk scatter | 5 v->vt transposed.
// ---------------------------------------------------------------------------
template<int MODE>
static __device__ __forceinline__ void mgemm_body(
    int bx, int by,
    const unsigned short* __restrict__ A, const unsigned short* __restrict__ Wt,
    const float* __restrict__ bias, const float* __restrict__ bias2,
    float* __restrict__ C, unsigned short* __restrict__ Cb,
    int M, int K, int Nc, int lda,
    unsigned short* __restrict__ u0, unsigned short* __restrict__ u1,
    unsigned short* __restrict__ u2)
{
    const int t    = threadIdx.x;
    const int wv   = t >> 6;
    const int lane = t & 63;
    const int g    = lane >> 4;
    const int lo   = lane & 15;
    const int wr   = wv >> 1;
    const int wc   = wv & 1;
    const int r0   = by * 128 + wr * 64;
    const int c0   = bx * 128 + wc * 64;

    f32x4 acc[4][4];
    #pragma unroll
    for (int i = 0; i < 4; ++i)
        #pragma unroll
        for (int j = 0; j < 4; ++j)
            #pragma unroll
            for (int r = 0; r < 4; ++r) acc[i][j][r] = 0.f;

    const unsigned short* aP[4];
    const unsigned short* bP[4];
    #pragma unroll
    for (int i = 0; i < 4; ++i) {
        aP[i] = A  + (size_t)(r0 + 16 * i + lo) * lda + g * 8;
        bP[i] = Wt + (size_t)(c0 + 16 * i + lo) * K + g * 8;
    }

    bf16x8 aA[4], bA[4], aB[4], bB[4];
    #pragma unroll
    for (int i = 0; i < 4; ++i) {
        aA[i] = *(const bf16x8*)(aP[i]);
        bA[i] = *(const bf16x8*)(bP[i]);
    }

    for (int k0 = 0; k0 < K; k0 += 64) {
        #pragma unroll
        for (int i = 0; i < 4; ++i) {
            aB[i] = *(const bf16x8*)(aP[i] + k0 + 32);
            bB[i] = *(const bf16x8*)(bP[i] + k0 + 32);
        }
        #pragma unroll
        for (int i = 0; i < 4; ++i)
            #pragma unroll
            for (int j = 0; j < 4; ++j)
                acc[i][j] = __builtin_amdgcn_mfma_f32_16x16x32_bf16(
                    aA[i], bA[j], acc[i][j], 0, 0, 0);
        if (k0 + 64 < K) {
            #pragma unroll
            for (int i = 0; i < 4; ++i) {
                aA[i] = *(const bf16x8*)(aP[i] + k0 + 64);
                bA[i] = *(const bf16x8*)(bP[i] + k0 + 64);
            }
        }
        #pragma unroll
        for (int i = 0; i < 4; ++i)
            #pragma unroll
            for (int j = 0; j < 4; ++j)
                acc[i][j] = __builtin_amdgcn_mfma_f32_16x16x32_bf16(
                    aB[i], bB[j], acc[i][j], 0, 0, 0);
    }

    #pragma unroll
    for (int j = 0; j < 4; ++j) {
        const int col = c0 + 16 * j + lo;
        const float bs = bias[col] + ((MODE == 4) ? bias2[col] : 0.f);
        #pragma unroll
        for (int i = 0; i < 4; ++i) {
            if (MODE == 5) {
                const int row0 = r0 + 16 * i + g * 4;
                const int bb   = row0 >> 11;
                const int nn0  = row0 & (SEQ - 1);
                const int hh   = col >> 5;
                const int dh   = col & 31;
                uint2 pk;
                pk.x = bf16rne(acc[i][j][0] + bs) | (bf16rne(acc[i][j][1] + bs) << 16);
                pk.y = bf16rne(acc[i][j][2] + bs) | (bf16rne(acc[i][j][3] + bs) << 16);
                *(uint2*)&u2[(((size_t)bb * NHEAD + hh) * DHEAD + dh) * SEQ + nn0] = pk;
            } else {
                #pragma unroll
                for (int r = 0; r < 4; ++r) {
                    const int row = r0 + 16 * i + g * 4 + r;
                    float v = acc[i][j][r] + bs;
                    if (MODE == 0) {
                        C[(size_t)row * Nc + col] = v;
                    } else if (MODE == 1) {
                        Cb[(size_t)row * Nc + col] =
                            (unsigned short)bf16rne(fmaxf(v, 0.f));
                    } else {   // MODE 4
                        const int bb = row >> 11;
                        const int nn = row & (SEQ - 1);
                        const int which = col >> 8;
                        const int d  = col & 255;
                        const int hh = d >> 5;
                        const int dh = d & 31;
                        const size_t dst =
                            (((size_t)bb * NHEAD + hh) * SEQ + nn) * DHEAD + dh;
                        if (which == 0) {
                            u0[dst] = (unsigned short)bf16rne(v * CLSCALE);
                        } else {
                            u1[dst] = (unsigned short)bf16rne(v);
                        }
                    }
                }
            }
        }
    }
}

template<int MODE>
__global__ __launch_bounds__(256, 3) void mgemm_kernel(
    const unsigned short* __restrict__ A, const unsigned short* __restrict__ Wt,
    const float* __restrict__ bias, const float* __restrict__ bias2,
    float* __restrict__ C, unsigned short* __restrict__ Cb,
    int M, int K, int Nc, int lda,
    unsigned short* __restrict__ u0, unsigned short* __restrict__ u1,
    unsigned short* __restrict__ u2)
{
    mgemm_body<MODE>(blockIdx.x, blockIdx.y, A, Wt, bias, bias2, C, Cb,
                     M, K, Nc, lda, u0, u1, u2);
}

// merged qkv kernel: blocks [0,512) = qk GEMM; [512,768) = v GEMM.
__global__ __launch_bounds__(256, 3) void qkv_kernel(
    const unsigned short* __restrict__ acat,
    const unsigned short* __restrict__ wqk, const unsigned short* __restrict__ wv,
    const float* __restrict__ bqkv, const float* __restrict__ bpos,
    unsigned short* __restrict__ qb, unsigned short* __restrict__ kb,
    unsigned short* __restrict__ vt)
{
    const int b = blockIdx.x;
    if (b < 512) {
        mgemm_body<4>(b & 3, b >> 2, acat, wqk, bqkv, bpos, nullptr, nullptr,
                      MROWS, KCAT, 512, KCAT, qb, kb, nullptr);
    } else {
        const int b2 = b - 512;
        mgemm_body<5>(b2 & 1, b2 >> 1, acat, wv, bqkv + 512, nullptr,
                      nullptr, nullptr, MROWS, 256, 256, KCAT,
                      nullptr, nullptr, vt);
    }
}

// ---------------------------------------------------------------------------
// MFMA flash attention, 32x32 frags + K/V prefetch + SPLIT-K over keys.
// Grid 1024 = 64 bh x 8 qblk x 2 kh (XCD-swizzled) -> 4 blocks/CU,
// 4 waves/SIMD. Each block: keys [kh*1024, +1024) for its 256 q rows,
// writes UN-NORMALIZED fp32 partials accP[kh] + row sums lP[kh] (valid:
// static-max softmax makes partials additive; combine folded into LN1).
// Inner loop byte-identical to round-25 (proven).
// ---------------------------------------------------------------------------
__global__ __launch_bounds__(256) void attn_kernel(
    const unsigned short* __restrict__ Qb, const unsigned short* __restrict__ Kb,
    const unsigned short* __restrict__ Vt, const int* __restrict__ mask,
    float* __restrict__ accP, float* __restrict__ lP)
{
    __shared__ float bias_s[SEQ];        // 8 KB mask bias (0 / -3e38)

    const int t    = threadIdx.x;
    const int wv   = t >> 6;
    const int lane = t & 63;
    const int h    = lane >> 5;          // lane half
    const int ql   = lane & 31;          // q-in-tile / K-row / V-d row

    const int sb   = ((blockIdx.x & 7) << 7) | (blockIdx.x >> 3);  // XCD swizzle
    const int bh   = sb >> 4;            // 0..63
    const int qblk = (sb >> 1) & 7;      // 0..7
    const int kh   = sb & 1;             // key half
    const int bb   = bh >> 3;
    const int hh   = bh & 7;
    const int qt   = qblk * 256 + wv * 64;   // wave owns q rows qt..qt+63
    const int khoff = kh * (SEQ / 2);

    const int* mrow = mask + bb * SEQ;
    for (int i = t; i < SEQ; i += 256)
        bias_s[i] = mrow[i] ? -3.0e38f : 0.0f;
    __syncthreads();

    const unsigned short* Qh = Qb + (size_t)bh * SEQ * 32;
    const unsigned short* Kh = Kb + (size_t)bh * SEQ * 32;
    const unsigned short* Vh = Vt + (size_t)bh * 32 * SEQ;

    bf16x8 qf[2][2];
    #pragma unroll
    for (int i = 0; i < 2; ++i)
        #pragma unroll
        for (int dh = 0; dh < 2; ++dh)
            qf[i][dh] = *(const bf16x8*)&Qh[(size_t)(qt + 32 * i + ql) * 32 + 16 * dh + 8 * h];

    f32x16 acc[2];
    #pragma unroll
    for (int i = 0; i < 2; ++i)
        #pragma unroll
        for (int r = 0; r < 16; ++r) acc[i][r] = 0.f;
    float l[2] = {0.f, 0.f};

    // prologue: load first-step fragments
    bf16x8 kf0 = *(const bf16x8*)&Kh[(size_t)(khoff + ql) * 32 + 8 * h];
    bf16x8 kf1 = *(const bf16x8*)&Kh[(size_t)(khoff + ql) * 32 + 16 + 8 * h];
    bf16x8 vf0 = *(const bf16x8*)&Vh[(size_t)ql * SEQ + khoff + 8 * h];
    bf16x8 vf1 = *(const bf16x8*)&Vh[(size_t)ql * SEQ + khoff + 16 + 8 * h];

    for (int k0 = khoff; k0 < khoff + SEQ / 2; k0 += 32) {
        // prefetch next step (wrapped within full range; tail loads harmless)
        const int kn = (k0 + 32) & (SEQ - 1);
        bf16x8 nkf0 = *(const bf16x8*)&Kh[(size_t)(kn + ql) * 32 + 8 * h];
        bf16x8 nkf1 = *(const bf16x8*)&Kh[(size_t)(kn + ql) * 32 + 16 + 8 * h];
        bf16x8 nvf0 = *(const bf16x8*)&Vh[(size_t)ql * SEQ + kn + 8 * h];
        bf16x8 nvf1 = *(const bf16x8*)&Vh[(size_t)ql * SEQ + kn + 16 + 8 * h];

        f32x16 cbv;
        #pragma unroll
        for (int c = 0; c < 4; ++c) {
            f32x4 cb = *(const f32x4*)&bias_s[k0 + 4 * h + 8 * c];
            #pragma unroll
            for (int e = 0; e < 4; ++e) cbv[4 * c + e] = cb[e];
        }

        #pragma unroll
        for (int i = 0; i < 2; ++i) {
            __builtin_amdgcn_s_setprio(1);
            f32x16 s = __builtin_amdgcn_mfma_f32_32x32x16_bf16(
                kf0, qf[i][0], cbv, 0, 0, 0);
            s = __builtin_amdgcn_mfma_f32_32x32x16_bf16(
                kf1, qf[i][1], s, 0, 0, 0);
            __builtin_amdgcn_s_setprio(0);

            float p[16];
            float tl = 0.f;
            #pragma unroll
            for (int r = 0; r < 16; ++r) {
                p[r] = exp2_raw(s[r]);
                tl += p[r];
            }
            l[i] += tl;

            unsigned w00, w01, w10, w11, w20, w21, w30, w31;
            asm("v_cvt_pk_bf16_f32 %0, %1, %2" : "=v"(w00) : "v"(p[0]),  "v"(p[1]));
            asm("v_cvt_pk_bf16_f32 %0, %1, %2" : "=v"(w01) : "v"(p[2]),  "v"(p[3]));
            asm("v_cvt_pk_bf16_f32 %0, %1, %2" : "=v"(w10) : "v"(p[4]),  "v"(p[5]));
            asm("v_cvt_pk_bf16_f32 %0, %1, %2" : "=v"(w11) : "v"(p[6]),  "v"(p[7]));
            asm("v_cvt_pk_bf16_f32 %0, %1, %2" : "=v"(w20) : "v"(p[8]),  "v"(p[9]));
            asm("v_cvt_pk_bf16_f32 %0, %1, %2" : "=v"(w21) : "v"(p[10]), "v"(p[11]));
            asm("v_cvt_pk_bf16_f32 %0, %1, %2" : "=v"(w30) : "v"(p[12]), "v"(p[13]));
            asm("v_cvt_pk_bf16_f32 %0, %1, %2" : "=v"(w31) : "v"(p[14]), "v"(p[15]));
            asm volatile("v_permlane32_swap_b32 %0, %1" : "+v"(w00), "+v"(w10));
            asm volatile("v_permlane32_swap_b32 %0, %1" : "+v"(w01), "+v"(w11));
            asm volatile("v_permlane32_swap_b32 %0, %1" : "+v"(w20), "+v"(w30));
            asm volatile("v_permlane32_swap_b32 %0, %1" : "+v"(w21), "+v"(w31));
            union { unsigned u[4]; bf16x8 v; } pa, pb;
            pa.u[0] = w00; pa.u[1] = w01; pa.u[2] = w10; pa.u[3] = w11;
            pb.u[0] = w20; pb.u[1] = w21; pb.u[2] = w30; pb.u[3] = w31;

            __builtin_amdgcn_s_setprio(1);
            acc[i] = __builtin_amdgcn_mfma_f32_32x32x16_bf16(
                vf0, pa.v, acc[i], 0, 0, 0);
            acc[i] = __builtin_amdgcn_mfma_f32_32x32x16_bf16(
                vf1, pb.v, acc[i], 0, 0, 0);
            __builtin_amdgcn_s_setprio(0);
        }

        kf0 = nkf0; kf1 = nkf1; vf0 = nvf0; vf1 = nvf1;
    }

    // epilogue: finish l, store UN-NORMALIZED partials + l (no divide)
    float* accH = accP + (size_t)kh * SZE;
    #pragma unroll
    for (int i = 0; i < 2; ++i) {
        l[i] += __shfl_xor(l[i], 32);
        if (h == 0)
            lP[(size_t)kh * 64 * SEQ + (size_t)bh * SEQ + qt + 32 * i + ql] = l[i];
        const size_t rowoff = (size_t)(bb * SEQ + qt + 32 * i + ql) * DIM + hh * 32;
        #pragma unroll
        for (int c = 0; c < 4; ++c) {
            float4 ov;
            ov.x = acc[i][4 * c + 0];
            ov.y = acc[i][4 * c + 1];
            ov.z = acc[i][4 * c + 2];
            ov.w = acc[i][4 * c + 3];
            *(float4*)&accH[rowoff + 4 * h + 8 * c] = ov;
        }
    }
}

// ---------------------------------------------------------------------------
// LN1 + split-K combine: h = LN(x + (A0+A1)/(l0+l1)). 1 wave = 1 row.
// Outputs fp32 hbuf + bf16 hb.  (Proven in round 21.)
// ---------------------------------------------------------------------------
__global__ __launch_bounds__(256) void ln1c_kernel(
    const float* __restrict__ X, const float* __restrict__ accP,
    const float* __restrict__ lP,
    const float* __restrict__ gam, const float* __restrict__ bet,
    float* __restrict__ Y, unsigned short* __restrict__ Yb)
{
    const int lane = threadIdx.x & 63;
    const int row  = blockIdx.x * 4 + (threadIdx.x >> 6);
    const size_t off = (size_t)row * DIM + lane * 4;

    const int hd  = lane >> 3;           // head for this lane's 4 cols
    const int bbv = row >> 11;
    const int nn  = row & (SEQ - 1);
    const size_t bhn = ((size_t)bbv * NHEAD + hd) * SEQ + nn;
    const float ls = lP[bhn] + lP[(size_t)64 * SEQ + bhn];
    const float inv = (ls > 0.f) ? 1.0f / ls : 0.f;

    float4 xv = *(const float4*)&X[off];
    float4 a0 = *(const float4*)&accP[off];
    float4 a1 = *(const float4*)&accP[SZE + off];
    float4 v;
    v.x = xv.x + (a0.x + a1.x) * inv;
    v.y = xv.y + (a0.y + a1.y) * inv;
    v.z = xv.z + (a0.z + a1.z) * inv;
    v.w = xv.w + (a0.w + a1.w) * inv;

    float s = (v.x + v.y) + (v.z + v.w);
    #pragma unroll
    for (int o = 1; o < 64; o <<= 1) s += __shfl_xor(s, o);
    const float mu = s * (1.f / 256.f);

    float4 d;
    d.x = v.x - mu; d.y = v.y - mu; d.z = v.z - mu; d.w = v.w - mu;
    float s2 = (d.x * d.x + d.y * d.y) + (d.z * d.z + d.w * d.w);
    #pragma unroll
    for (int o = 1; o < 64; o <<= 1) s2 += __shfl_xor(s2, o);
    const float rs = rsqrtf(s2 * (1.f / 256.f) + 1e-5f);

    float4 gv = *(const float4*)&gam[lane * 4];
    float4 bv = *(const float4*)&bet[lane * 4];
    float4 y;
    y.x = d.x * rs * gv.x + bv.x;
    y.y = d.y * rs * gv.y + bv.y;
    y.z = d.z * rs * gv.z + bv.z;
    y.w = d.w * rs * gv.w + bv.w;
    *(float4*)&Y[off] = y;

    uint2 pk;
    pk.x = bf16rne(y.x) | (bf16rne(y.y) << 16);
    pk.y = bf16rne(y.z) | (bf16rne(y.w) << 16);
    *(uint2*)&Yb[off] = pk;
}

// ---------------------------------------------------------------------------
// Fused residual + LayerNorm (LN2): 1 wave = 1 row, shfl-only.
// ---------------------------------------------------------------------------
__global__ __launch_bounds__(256) void ln_kernel(
    const float* __restrict__ X, const float* __restrict__ R,
    const float* __restrict__ gam, const float* __restrict__ bet,
    float* __restrict__ Y)
{
    const int lane = threadIdx.x & 63;
    const int row  = blockIdx.x * 4 + (threadIdx.x >> 6);
    const size_t off = (size_t)row * DIM + lane * 4;

    float4 xv = *(const float4*)&X[off];
    float4 rv = *(const float4*)&R[off];
    float4 v;
    v.x = xv.x + rv.x; v.y = xv.y + rv.y;
    v.z = xv.z + rv.z; v.w = xv.w + rv.w;

    float s = (v.x + v.y) + (v.z + v.w);
    #pragma unroll
    for (int o = 1; o < 64; o <<= 1) s += __shfl_xor(s, o);
    const float mu = s * (1.f / 256.f);

    float4 d;
    d.x = v.x - mu; d.y = v.y - mu; d.z = v.z - mu; d.w = v.w - mu;
    float s2 = (d.x * d.x + d.y * d.y) + (d.z * d.z + d.w * d.w);
    #pragma unroll
    for (int o = 1; o < 64; o <<= 1) s2 += __shfl_xor(s2, o);
    const float rs = rsqrtf(s2 * (1.f / 256.f) + 1e-5f);

    float4 gv = *(const float4*)&gam[lane * 4];
    float4 bv = *(const float4*)&bet[lane * 4];
    float4 y;
    y.x = d.x * rs * gv.x + bv.x;
    y.y = d.y * rs * gv.y + bv.y;
    y.z = d.z * rs * gv.z + bv.z;
    y.w = d.w * rs * gv.w + bv.w;
    *(float4*)&Y[off] = y;
}

// ---------------------------------------------------------------------------
extern "C" void kernel_launch(void* const* d_in, const int* in_sizes, int n_in,
                              void* d_out, int out_size, void* d_ws, size_t ws_size,
                              hipStream_t stream)
{
    const float* x    = (const float*)d_in[0];
    const float* pos  = (const float*)d_in[1];
    const int*   mask = (const int*)d_in[2];
    const float* Wqkv = (const float*)d_in[3];
    const float* bqkv = (const float*)d_in[4];
    const float* Wpos = (const float*)d_in[5];
    const float* bpos = (const float*)d_in[6];
    const float* ln1g = (const float*)d_in[7];
    const float* ln1b = (const float*)d_in[8];
    const float* W1   = (const float*)d_in[9];
    const float* b1   = (const float*)d_in[10];
    const float* W2   = (const float*)d_in[11];
    const float* b2   = (const float*)d_in[12];
    const float* ln2g = (const float*)d_in[13];
    const float* ln2b = (const float*)d_in[14];
    float* out = (float*)d_out;

    // Workspace layout (~94 MB), regions reused by lifetime:
    //  [ 0,34M)  acat bf16 (s1-3) | accP fp32 2x16.8M (s5-6) | mid bf16 (s7-8)
    //  [34,42M)  qb (s3-5)   [42,50M) kb (s3-5)   [58,66M) vt (s3-5)
    //  [66,74M)  hb bf16 (s6-7)
    //  [74,90M)  hbuf fp32 (s6-9)
    //  [90,92M)  weights: wqk[512,768], wv[256,256], w1[1024,256], w2[256,1024]
    //  [93,94M)  lP fp32 [2][64][2048]
    //  f2 lives in d_out (written s8, LN2 in-place s9).
    char* base = (char*)d_ws;
    const size_t MB = 1024 * 1024;
    unsigned short* acat = (unsigned short*)(base + 0);
    float*          accP = (float*)(base + 0);
    unsigned short* mid  = (unsigned short*)(base + 0);
    unsigned short* qb   = (unsigned short*)(base + 34 * MB);
    unsigned short* kb   = (unsigned short*)(base + 42 * MB);
    unsigned short* vt   = (unsigned short*)(base + 58 * MB);
    unsigned short* hb   = (unsigned short*)(base + 66 * MB);
    float*          hbuf = (float*)(base + 74 * MB);
    unsigned short* wqk  = (unsigned short*)(base + 90 * MB);   // [512,768]
    unsigned short* wv   = wqk + 512 * 768;                     // [256,256]
    unsigned short* w1   = wv + 256 * 256;                      // [1024,256]
    unsigned short* w2   = w1 + 1024 * 256;                     // [256,1024]
    float*          lP   = (float*)(base + 93 * MB);            // 1 MB
    float*          f2   = out;

    dim3 blk(256);

    // s1) x,pos -> concatenated bf16 acat[M,768]
    convcat_kernel<<<dim3((3 * (int)(SZE / 8)) / 256), blk, 0, stream>>>(
        x, pos, acat, (int)(SZE / 8), (int)(2 * SZE / 8));
    // s2) all weight transposes, one launch (960 blocks)
    wtrans_all_kernel<<<dim3(960), blk, 0, stream>>>(
        Wqkv, Wpos, W1, W2, wqk, wv, w1, w2);
    // s3) merged qk + v GEMMs, one launch (768 blocks)
    qkv_kernel<<<dim3(768), blk, 0, stream>>>(
        acat, wqk, wv, bqkv, bpos, qb, kb, vt);
    // s5) split-K attention -> accP, lP  (grid 1024, 4 waves/SIMD)
    attn_kernel<<<dim3(1024), blk, 0, stream>>>(
        qb, kb, vt, mask, accP, lP);
    // s6) h = LN(x + combine(accP,lP)) -> hbuf fp32 + hb bf16
    ln1c_kernel<<<dim3(MROWS / 4), blk, 0, stream>>>(
        x, accP, lP, ln1g, ln1b, hbuf, hb);
    // s7) relu(h @ W1 + b1) -> mid bf16
    mgemm_kernel<1><<<dim3(1024 / 128, MROWS / 128), blk, 0, stream>>>(
        hb, w1, b1, nullptr, nullptr, mid, MROWS, 256, 1024, 256,
        nullptr, nullptr, nullptr);
    // s8) mid @ W2 + b2 -> f2 (= d_out)
    mgemm_kernel<0><<<dim3(256 / 128, MROWS / 128), blk, 0, stream>>>(
        mid, w2, b2, nullptr, f2, nullptr, MROWS, 1024, 256, 1024,
        nullptr, nullptr, nullptr);
    // s9) out = LN(h + ffn), in-place on d_out
    ln_kernel<<<dim3(MROWS / 4), blk, 0, stream>>>(hbuf, f2, ln2g, ln2b, out);
}

// Round 27
// 232.896 us; speedup vs baseline: 1.0135x; 1.0135x over previous
//
#include <hip/hip_runtime.h>
#include <math.h>

// Problem constants (B=8, N=2048, D=256, H=8, Dh=32)
#define BATCH 8
#define SEQ   2048
#define DIM   256
#define NHEAD 8
#define DHEAD 32
#define MROWS (BATCH*SEQ)   // 16384
#define KCAT  768           // concatenated qkv/pos K-dim

typedef short bf16x8 __attribute__((ext_vector_type(8)));
typedef float f32x4  __attribute__((ext_vector_type(4)));
typedef float f32x16 __attribute__((ext_vector_type(16)));

#define CLSCALE 0.25503485f   // log2(e)/sqrt(32): Q pre-scaled by this in mgemm

// raw hardware exp2 (single v_exp_f32; inputs are bounded log2-units,
// masked scores are -3e38 -> exp2 -> 0; no range reduction needed)
static __device__ __forceinline__ float exp2_raw(float x) {
    float r;
    asm("v_exp_f32 %0, %1" : "=v"(r) : "v"(x));
    return r;
}

// fp32 -> bf16 round-to-nearest-even (bits)
static __device__ __forceinline__ unsigned bf16rne(float f) {
    unsigned u = __float_as_uint(f);
    return (u + 0x7FFFu + ((u >> 16) & 1u)) >> 16;
}

// ---------------------------------------------------------------------------
// Fused preprocessing, ONE launch (7104 blocks):
//   blocks [0,6144): x,pos -> concatenated bf16 acat[M,768]
//   blocks [6144,7104): all 5 weight transposes (32x32 LDS tiles)
// ---------------------------------------------------------------------------
__global__ __launch_bounds__(256) void prep_kernel(
    const float* __restrict__ x, const float* __restrict__ pos,
    unsigned short* __restrict__ acat, int n1, int n2,
    const float* __restrict__ Wqkv, const float* __restrict__ Wpos,
    const float* __restrict__ W1, const float* __restrict__ W2,
    unsigned short* __restrict__ wqk, unsigned short* __restrict__ wv,
    unsigned short* __restrict__ w1, unsigned short* __restrict__ w2)
{
    __shared__ float tile[32][33];
    if (blockIdx.x < 6144) {
        // ---- convcat part ----
        int i = blockIdx.x * 256 + threadIdx.x;
        const float* s; size_t dst; int j;
        if (i < n1) {
            j = i; s = x;
            int row = j >> 5, c8 = (j & 31) * 8;
            dst = (size_t)row * KCAT + c8;
        } else {
            j = i - n1; if (j >= n2) return; s = pos;
            int row = j >> 6, c8 = (j & 63) * 8;
            dst = (size_t)row * KCAT + 256 + c8;
        }
        float4 a = ((const float4*)s)[2 * j];
        float4 b = ((const float4*)s)[2 * j + 1];
        union { unsigned short u[8]; uint4 v; } o;
        o.u[0] = bf16rne(a.x); o.u[1] = bf16rne(a.y);
        o.u[2] = bf16rne(a.z); o.u[3] = bf16rne(a.w);
        o.u[4] = bf16rne(b.x); o.u[5] = bf16rne(b.y);
        o.u[6] = bf16rne(b.z); o.u[7] = bf16rne(b.w);
        *(uint4*)&acat[dst] = o.v;
    } else {
        // ---- wtrans part ----
        int b = blockIdx.x - 6144;
        const float* src; unsigned short* dst;
        int srcN, srcColOff, dstK, dstKOff, nbx;
        if (b < 128)      {          src = Wqkv; dst = wqk; srcN = 768;  srcColOff = 0;   dstK = 768;  dstKOff = 0;   nbx = 16; }
        else if (b < 384) { b -= 128; src = Wpos; dst = wqk; srcN = 512;  srcColOff = 0;   dstK = 768;  dstKOff = 256; nbx = 16; }
        else if (b < 448) { b -= 384; src = Wqkv; dst = wv;  srcN = 768;  srcColOff = 512; dstK = 256;  dstKOff = 0;   nbx = 8;  }
        else if (b < 704) { b -= 448; src = W1;   dst = w1;  srcN = 1024; srcColOff = 0;   dstK = 256;  dstKOff = 0;   nbx = 32; }
        else              { b -= 704; src = W2;   dst = w2;  srcN = 256;  srcColOff = 0;   dstK = 1024; dstKOff = 0;   nbx = 8;  }
        const int tn0 = (b % nbx) * 32;
        const int tk0 = (b / nbx) * 32;
        const int tx = threadIdx.x & 31;
        const int ty = threadIdx.x >> 5;
        #pragma unroll
        for (int r = ty; r < 32; r += 8)
            tile[r][tx] = src[(size_t)(tk0 + r) * srcN + srcColOff + tn0 + tx];
        __syncthreads();
        #pragma unroll
        for (int r = ty; r < 32; r += 8)
            dst[(size_t)(tn0 + r) * dstK + dstKOff + tk0 + tx] =
                (unsigned short)bf16rne(tile[tx][r]);
    }
}

// ---------------------------------------------------------------------------
// bf16 MFMA GEMM body (device fn): C[M,Nc] = A[M,K] @ Wt[Nc,K]^T + bias.
// 128x128 tile at (bx,by), 4 waves 2x2, 4x4 frags of 16x16x32.
// Modes: 0 fp32 store | 1 relu->bf16 | 4 qk scatter | 5 v->vt transposed.
// ---------------------------------------------------------------------------
template<int MODE>
static __device__ __forceinline__ void mgemm_body(
    int bx, int by,
    const unsigned short* __restrict__ A, const unsigned short* __restrict__ Wt,
    const float* __restrict__ bias, const float* __restrict__ bias2,
    float* __restrict__ C, unsigned short* __restrict__ Cb,
    int M, int K, int Nc, int lda,
    unsigned short* __restrict__ u0, unsigned short* __restrict__ u1,
    unsigned short* __restrict__ u2)
{
    const int t    = threadIdx.x;
    const int wv   = t >> 6;
    const int lane = t & 63;
    const int g    = lane >> 4;
    const int lo   = lane & 15;
    const int wr   = wv >> 1;
    const int wc   = wv & 1;
    const int r0   = by * 128 + wr * 64;
    const int c0   = bx * 128 + wc * 64;

    f32x4 acc[4][4];
    #pragma unroll
    for (int i = 0; i < 4; ++i)
        #pragma unroll
        for (int j = 0; j < 4; ++j)
            #pragma unroll
            for (int r = 0; r < 4; ++r) acc[i][j][r] = 0.f;

    const unsigned short* aP[4];
    const unsigned short* bP[4];
    #pragma unroll
    for (int i = 0; i < 4; ++i) {
        aP[i] = A  + (size_t)(r0 + 16 * i + lo) * lda + g * 8;
        bP[i] = Wt + (size_t)(c0 + 16 * i + lo) * K + g * 8;
    }

    bf16x8 aA[4], bA[4], aB[4], bB[4];
    #pragma unroll
    for (int i = 0; i < 4; ++i) {
        aA[i] = *(const bf16x8*)(aP[i]);
        bA[i] = *(const bf16x8*)(bP[i]);
    }

    for (int k0 = 0; k0 < K; k0 += 64) {
        #pragma unroll
        for (int i = 0; i < 4; ++i) {
            aB[i] = *(const bf16x8*)(aP[i] + k0 + 32);
            bB[i] = *(const bf16x8*)(bP[i] + k0 + 32);
        }
        #pragma unroll
        for (int i = 0; i < 4; ++i)
            #pragma unroll
            for (int j = 0; j < 4; ++j)
                acc[i][j] = __builtin_amdgcn_mfma_f32_16x16x32_bf16(
                    aA[i], bA[j], acc[i][j], 0, 0, 0);
        if (k0 + 64 < K) {
            #pragma unroll
            for (int i = 0; i < 4; ++i) {
                aA[i] = *(const bf16x8*)(aP[i] + k0 + 64);
                bA[i] = *(const bf16x8*)(bP[i] + k0 + 64);
            }
        }
        #pragma unroll
        for (int i = 0; i < 4; ++i)
            #pragma unroll
            for (int j = 0; j < 4; ++j)
                acc[i][j] = __builtin_amdgcn_mfma_f32_16x16x32_bf16(
                    aB[i], bB[j], acc[i][j], 0, 0, 0);
    }

    #pragma unroll
    for (int j = 0; j < 4; ++j) {
        const int col = c0 + 16 * j + lo;
        const float bs = bias[col] + ((MODE == 4) ? bias2[col] : 0.f);
        #pragma unroll
        for (int i = 0; i < 4; ++i) {
            if (MODE == 5) {
                const int row0 = r0 + 16 * i + g * 4;
                const int bb   = row0 >> 11;
                const int nn0  = row0 & (SEQ - 1);
                const int hh   = col >> 5;
                const int dh   = col & 31;
                uint2 pk;
                pk.x = bf16rne(acc[i][j][0] + bs) | (bf16rne(acc[i][j][1] + bs) << 16);
                pk.y = bf16rne(acc[i][j][2] + bs) | (bf16rne(acc[i][j][3] + bs) << 16);
                *(uint2*)&u2[(((size_t)bb * NHEAD + hh) * DHEAD + dh) * SEQ + nn0] = pk;
            } else {
                #pragma unroll
                for (int r = 0; r < 4; ++r) {
                    const int row = r0 + 16 * i + g * 4 + r;
                    float v = acc[i][j][r] + bs;
                    if (MODE == 0) {
                        C[(size_t)row * Nc + col] = v;
                    } else if (MODE == 1) {
                        Cb[(size_t)row * Nc + col] =
                            (unsigned short)bf16rne(fmaxf(v, 0.f));
                    } else {   // MODE 4
                        const int bb = row >> 11;
                        const int nn = row & (SEQ - 1);
                        const int which = col >> 8;
                        const int d  = col & 255;
                        const int hh = d >> 5;
                        const int dh = d & 31;
                        const size_t dst =
                            (((size_t)bb * NHEAD + hh) * SEQ + nn) * DHEAD + dh;
                        if (which == 0) {
                            u0[dst] = (unsigned short)bf16rne(v * CLSCALE);
                        } else {
                            u1[dst] = (unsigned short)bf16rne(v);
                        }
                    }
                }
            }
        }
    }
}

template<int MODE>
__global__ __launch_bounds__(256, 3) void mgemm_kernel(
    const unsigned short* __restrict__ A, const unsigned short* __restrict__ Wt,
    const float* __restrict__ bias, const float* __restrict__ bias2,
    float* __restrict__ C, unsigned short* __restrict__ Cb,
    int M, int K, int Nc, int lda,
    unsigned short* __restrict__ u0, unsigned short* __restrict__ u1,
    unsigned short* __restrict__ u2)
{
    mgemm_body<MODE>(blockIdx.x, blockIdx.y, A, Wt, bias, bias2, C, Cb,
                     M, K, Nc, lda, u0, u1, u2);
}

// merged qkv kernel: blocks [0,512) = qk GEMM; [512,768) = v GEMM.
__global__ __launch_bounds__(256, 3) void qkv_kernel(
    const unsigned short* __restrict__ acat,
    const unsigned short* __restrict__ wqk, const unsigned short* __restrict__ wv,
    const float* __restrict__ bqkv, const float* __restrict__ bpos,
    unsigned short* __restrict__ qb, unsigned short* __restrict__ kb,
    unsigned short* __restrict__ vt)
{
    const int b = blockIdx.x;
    if (b < 512) {
        mgemm_body<4>(b & 3, b >> 2, acat, wqk, bqkv, bpos, nullptr, nullptr,
                      MROWS, KCAT, 512, KCAT, qb, kb, nullptr);
    } else {
        const int b2 = b - 512;
        mgemm_body<5>(b2 & 1, b2 >> 1, acat, wv, bqkv + 512, nullptr,
                      nullptr, nullptr, MROWS, 256, 256, KCAT,
                      nullptr, nullptr, vt);
    }
}

// ---------------------------------------------------------------------------
// MFMA flash attention, 32x32 fragments + K/V register prefetch (round-25,
// proven 79 us). Wave = 2 q-tiles of 32 (64 q rows), block = 4 waves,
// grid 512 = 64 bh x 8 qblk (XCD-swizzled). Swapped QK^T at 32x32
// (S^T = K·Q^T, col=lane&31=q, row=key=(r&3)+8(r>>2)+4h). PV B-frags via
// 4 v_permlane32_swap/tile (DS idle). Static-max softmax. O^T direct f4
// stores. Next step's K/V loads issue before computing the current step.
// ---------------------------------------------------------------------------
__global__ __launch_bounds__(256) void attn_kernel(
    const unsigned short* __restrict__ Qb, const unsigned short* __restrict__ Kb,
    const unsigned short* __restrict__ Vt, const int* __restrict__ mask,
    float* __restrict__ O)
{
    __shared__ float bias_s[SEQ];        // 8 KB mask bias (0 / -3e38)

    const int t    = threadIdx.x;
    const int wv   = t >> 6;
    const int lane = t & 63;
    const int h    = lane >> 5;          // lane half
    const int ql   = lane & 31;          // q-in-tile / K-row / V-d row

    const int sb   = ((blockIdx.x & 7) << 6) | (blockIdx.x >> 3);  // XCD swizzle
    const int bh   = sb >> 3;            // 0..63
    const int qblk = sb & 7;             // 0..7
    const int bb   = bh >> 3;
    const int hh   = bh & 7;
    const int qt   = qblk * 256 + wv * 64;   // wave owns q rows qt..qt+63

    const int* mrow = mask + bb * SEQ;
    for (int i = t; i < SEQ; i += 256)
        bias_s[i] = mrow[i] ? -3.0e38f : 0.0f;
    __syncthreads();

    const unsigned short* Qh = Qb + (size_t)bh * SEQ * 32;
    const unsigned short* Kh = Kb + (size_t)bh * SEQ * 32;
    const unsigned short* Vh = Vt + (size_t)bh * 32 * SEQ;

    bf16x8 qf[2][2];
    #pragma unroll
    for (int i = 0; i < 2; ++i)
        #pragma unroll
        for (int dh = 0; dh < 2; ++dh)
            qf[i][dh] = *(const bf16x8*)&Qh[(size_t)(qt + 32 * i + ql) * 32 + 16 * dh + 8 * h];

    f32x16 acc[2];
    #pragma unroll
    for (int i = 0; i < 2; ++i)
        #pragma unroll
        for (int r = 0; r < 16; ++r) acc[i][r] = 0.f;
    float l[2] = {0.f, 0.f};

    // prologue: load step-0 fragments
    bf16x8 kf0 = *(const bf16x8*)&Kh[(size_t)ql * 32 + 8 * h];
    bf16x8 kf1 = *(const bf16x8*)&Kh[(size_t)ql * 32 + 16 + 8 * h];
    bf16x8 vf0 = *(const bf16x8*)&Vh[(size_t)ql * SEQ + 8 * h];
    bf16x8 vf1 = *(const bf16x8*)&Vh[(size_t)ql * SEQ + 16 + 8 * h];

    for (int k0 = 0; k0 < SEQ; k0 += 32) {
        // ---- prefetch next step (wrapped; harmless dead loads at tail) ----
        const int kn = (k0 + 32) & (SEQ - 1);
        bf16x8 nkf0 = *(const bf16x8*)&Kh[(size_t)(kn + ql) * 32 + 8 * h];
        bf16x8 nkf1 = *(const bf16x8*)&Kh[(size_t)(kn + ql) * 32 + 16 + 8 * h];
        bf16x8 nvf0 = *(const bf16x8*)&Vh[(size_t)ql * SEQ + kn + 8 * h];
        bf16x8 nvf1 = *(const bf16x8*)&Vh[(size_t)ql * SEQ + kn + 16 + 8 * h];

        f32x16 cbv;
        #pragma unroll
        for (int c = 0; c < 4; ++c) {
            f32x4 cb = *(const f32x4*)&bias_s[k0 + 4 * h + 8 * c];
            #pragma unroll
            for (int e = 0; e < 4; ++e) cbv[4 * c + e] = cb[e];
        }

        #pragma unroll
        for (int i = 0; i < 2; ++i) {
            __builtin_amdgcn_s_setprio(1);
            f32x16 s = __builtin_amdgcn_mfma_f32_32x32x16_bf16(
                kf0, qf[i][0], cbv, 0, 0, 0);
            s = __builtin_amdgcn_mfma_f32_32x32x16_bf16(
                kf1, qf[i][1], s, 0, 0, 0);
            __builtin_amdgcn_s_setprio(0);

            float p[16];
            float tl = 0.f;
            #pragma unroll
            for (int r = 0; r < 16; ++r) {
                p[r] = exp2_raw(s[r]);
                tl += p[r];
            }
            l[i] += tl;

            unsigned w00, w01, w10, w11, w20, w21, w30, w31;
            asm("v_cvt_pk_bf16_f32 %0, %1, %2" : "=v"(w00) : "v"(p[0]),  "v"(p[1]));
            asm("v_cvt_pk_bf16_f32 %0, %1, %2" : "=v"(w01) : "v"(p[2]),  "v"(p[3]));
            asm("v_cvt_pk_bf16_f32 %0, %1, %2" : "=v"(w10) : "v"(p[4]),  "v"(p[5]));
            asm("v_cvt_pk_bf16_f32 %0, %1, %2" : "=v"(w11) : "v"(p[6]),  "v"(p[7]));
            asm("v_cvt_pk_bf16_f32 %0, %1, %2" : "=v"(w20) : "v"(p[8]),  "v"(p[9]));
            asm("v_cvt_pk_bf16_f32 %0, %1, %2" : "=v"(w21) : "v"(p[10]), "v"(p[11]));
            asm("v_cvt_pk_bf16_f32 %0, %1, %2" : "=v"(w30) : "v"(p[12]), "v"(p[13]));
            asm("v_cvt_pk_bf16_f32 %0, %1, %2" : "=v"(w31) : "v"(p[14]), "v"(p[15]));
            asm volatile("v_permlane32_swap_b32 %0, %1" : "+v"(w00), "+v"(w10));
            asm volatile("v_permlane32_swap_b32 %0, %1" : "+v"(w01), "+v"(w11));
            asm volatile("v_permlane32_swap_b32 %0, %1" : "+v"(w20), "+v"(w30));
            asm volatile("v_permlane32_swap_b32 %0, %1" : "+v"(w21), "+v"(w31));
            union { unsigned u[4]; bf16x8 v; } pa, pb;
            pa.u[0] = w00; pa.u[1] = w01; pa.u[2] = w10; pa.u[3] = w11;
            pb.u[0] = w20; pb.u[1] = w21; pb.u[2] = w30; pb.u[3] = w31;

            __builtin_amdgcn_s_setprio(1);
            acc[i] = __builtin_amdgcn_mfma_f32_32x32x16_bf16(
                vf0, pa.v, acc[i], 0, 0, 0);
            acc[i] = __builtin_amdgcn_mfma_f32_32x32x16_bf16(
                vf1, pb.v, acc[i], 0, 0, 0);
            __builtin_amdgcn_s_setprio(0);
        }

        // ---- rotate prefetched fragments in ----
        kf0 = nkf0; kf1 = nkf1; vf0 = nvf0; vf1 = nvf1;
    }

    #pragma unroll
    for (int i = 0; i < 2; ++i) {
        l[i] += __shfl_xor(l[i], 32);
        const float inv = (l[i] > 0.f) ? 1.0f / l[i] : 0.f;
        const size_t rowoff = (size_t)(bb * SEQ + qt + 32 * i + ql) * DIM + hh * 32;
        #pragma unroll
        for (int c = 0; c < 4; ++c) {
            float4 ov;
            ov.x = acc[i][4 * c + 0] * inv;
            ov.y = acc[i][4 * c + 1] * inv;
            ov.z = acc[i][4 * c + 2] * inv;
            ov.w = acc[i][4 * c + 3] * inv;
            *(float4*)&O[rowoff + 4 * h + 8 * c] = ov;
        }
    }
}

// ---------------------------------------------------------------------------
// Fused residual + LayerNorm: 1 wave = 1 row, shfl-only. Optional bf16 out.
// ---------------------------------------------------------------------------
__global__ __launch_bounds__(256) void ln_kernel(
    const float* __restrict__ X, const float* __restrict__ R,
    const float* __restrict__ gam, const float* __restrict__ bet,
    float* __restrict__ Y, unsigned short* __restrict__ Yb)
{
    const int lane = threadIdx.x & 63;
    const int row  = blockIdx.x * 4 + (threadIdx.x >> 6);
    const size_t off = (size_t)row * DIM + lane * 4;

    float4 xv = *(const float4*)&X[off];
    float4 rv = *(const float4*)&R[off];
    float4 v;
    v.x = xv.x + rv.x; v.y = xv.y + rv.y;
    v.z = xv.z + rv.z; v.w = xv.w + rv.w;

    float s = (v.x + v.y) + (v.z + v.w);
    #pragma unroll
    for (int o = 1; o < 64; o <<= 1) s += __shfl_xor(s, o);
    const float mu = s * (1.f / 256.f);

    float4 d;
    d.x = v.x - mu; d.y = v.y - mu; d.z = v.z - mu; d.w = v.w - mu;
    float s2 = (d.x * d.x + d.y * d.y) + (d.z * d.z + d.w * d.w);
    #pragma unroll
    for (int o = 1; o < 64; o <<= 1) s2 += __shfl_xor(s2, o);
    const float rs = rsqrtf(s2 * (1.f / 256.f) + 1e-5f);

    float4 gv = *(const float4*)&gam[lane * 4];
    float4 bv = *(const float4*)&bet[lane * 4];
    float4 y;
    y.x = d.x * rs * gv.x + bv.x;
    y.y = d.y * rs * gv.y + bv.y;
    y.z = d.z * rs * gv.z + bv.z;
    y.w = d.w * rs * gv.w + bv.w;
    *(float4*)&Y[off] = y;

    if (Yb) {
        uint2 pk;
        pk.x = bf16rne(y.x) | (bf16rne(y.y) << 16);
        pk.y = bf16rne(y.z) | (bf16rne(y.w) << 16);
        *(uint2*)&Yb[off] = pk;
    }
}

// ---------------------------------------------------------------------------
extern "C" void kernel_launch(void* const* d_in, const int* in_sizes, int n_in,
                              void* d_out, int out_size, void* d_ws, size_t ws_size,
                              hipStream_t stream)
{
    const float* x    = (const float*)d_in[0];
    const float* pos  = (const float*)d_in[1];
    const int*   mask = (const int*)d_in[2];
    const float* Wqkv = (const float*)d_in[3];
    const float* bqkv = (const float*)d_in[4];
    const float* Wpos = (const float*)d_in[5];
    const float* bpos = (const float*)d_in[6];
    const float* ln1g = (const float*)d_in[7];
    const float* ln1b = (const float*)d_in[8];
    const float* W1   = (const float*)d_in[9];
    const float* b1   = (const float*)d_in[10];
    const float* W2   = (const float*)d_in[11];
    const float* b2   = (const float*)d_in[12];
    const float* ln2g = (const float*)d_in[13];
    const float* ln2b = (const float*)d_in[14];
    float* out = (float*)d_out;

    // Workspace layout (~92 MB), regions reused by lifetime (round-20 map)
    char* base = (char*)d_ws;
    const size_t MB = 1024 * 1024;
    const size_t SZ = (size_t)MROWS * DIM;           // 4,194,304 elements
    unsigned short* acat = (unsigned short*)(base + 0);
    float*          ao   = (float*)(base + 0);
    unsigned short* mid  = (unsigned short*)(base + 0);
    unsigned short* qb   = (unsigned short*)(base + 34 * MB);
    unsigned short* kb   = (unsigned short*)(base + 42 * MB);
    unsigned short* vt   = (unsigned short*)(base + 58 * MB);
    unsigned short* hb   = (unsigned short*)(base + 66 * MB);
    float*          hbuf = (float*)(base + 74 * MB);
    unsigned short* wqk  = (unsigned short*)(base + 90 * MB);   // [512,768]
    unsigned short* wv   = wqk + 512 * 768;                     // [256,256]
    unsigned short* w1   = wv + 256 * 256;                      // [1024,256]
    unsigned short* w2   = w1 + 1024 * 256;                     // [256,1024]
    float*          f2   = out;

    dim3 blk(256);

    // s1) fused preprocessing: convcat (6144 blocks) + wtrans (960 blocks)
    prep_kernel<<<dim3(7104), blk, 0, stream>>>(
        x, pos, acat, (int)(SZ / 8), (int)(2 * SZ / 8),
        Wqkv, Wpos, W1, W2, wqk, wv, w1, w2);
    // s3) merged qk + v GEMMs, one launch (768 blocks)
    qkv_kernel<<<dim3(768), blk, 0, stream>>>(
        acat, wqk, wv, bqkv, bpos, qb, kb, vt);
    // s5) attention (32x32 frags, K/V prefetch) -> ao  (grid 512)
    attn_kernel<<<dim3(BATCH * NHEAD * (SEQ / 256)), blk, 0, stream>>>(
        qb, kb, vt, mask, ao);
    // s6) h = LN(x + ao) -> hbuf fp32 + hb bf16
    ln_kernel<<<dim3(MROWS / 4), blk, 0, stream>>>(x, ao, ln1g, ln1b, hbuf, hb);
    // s7) relu(h @ W1 + b1) -> mid bf16
    mgemm_kernel<1><<<dim3(1024 / 128, MROWS / 128), blk, 0, stream>>>(
        hb, w1, b1, nullptr, nullptr, mid, MROWS, 256, 1024, 256,
        nullptr, nullptr, nullptr);
    // s8) mid @ W2 + b2 -> f2 (= d_out)
    mgemm_kernel<0><<<dim3(256 / 128, MROWS / 128), blk, 0, stream>>>(
        mid, w2, b2, nullptr, f2, nullptr, MROWS, 1024, 256, 1024,
        nullptr, nullptr, nullptr);
    // s9) out = LN(h + ffn), in-place on d_out
    ln_kernel<<<dim3(MROWS / 4), blk, 0, stream>>>(hbuf, f2, ln2g, ln2b, out, nullptr);
}